// Round 18
// baseline (358.124 us; speedup 1.0000x reference)
//
#include <hip/hip_runtime.h>
#include <cstdint>

#define LN_EPS 1e-12f
#define NTOK 32768
#define HDIM 768
#define DDIM 16
#define MMEM 50

// ws layout (float offsets)
#define WS_G    0        // 16
#define WS_C    16       // 16 (includes b_down)
#define WS_KEY  32       // 800
#define WS_VAL  832      // 800
#define WS_WT   1632     // 12288 ushorts (bf16 W1^T [16][768]) = 3072 floats

typedef short bf16x8 __attribute__((ext_vector_type(8)));
typedef float f32x4 __attribute__((ext_vector_type(4)));

// bf16 via raw bits (RNE) — for weights
__device__ __forceinline__ unsigned f2bf(float f) {
    const unsigned u = __builtin_bit_cast(unsigned, f);
    return (u + 0x7FFFu + ((u >> 16) & 1u)) >> 16;
}

// 13 blocks: block 0 = G/C + KEY/VAL; blocks 1..12 = WT conversion slices.
__global__ __launch_bounds__(256) void pre_kernel(
    const float* __restrict__ g1, const float* __restrict__ b1,
    const float* __restrict__ W_down, const float* __restrict__ b_down,
    const float* __restrict__ memory, const float* __restrict__ W_k,
    const float* __restrict__ b_k, const float* __restrict__ W_v,
    const float* __restrict__ b_v, float* __restrict__ ws)
{
    const int tid = threadIdx.x;
    const int blk = blockIdx.x;
    if (blk > 0) {
        const int e0 = (blk - 1) * 1024 + tid * 4;
        const int n  = e0 / HDIM;
        const int h  = e0 - n * HDIM;
        const unsigned r0 = f2bf(g1[h+0]*W_down[(h+0)*DDIM+n])
                          | (f2bf(g1[h+1]*W_down[(h+1)*DDIM+n]) << 16);
        const unsigned r1 = f2bf(g1[h+2]*W_down[(h+2)*DDIM+n])
                          | (f2bf(g1[h+3]*W_down[(h+3)*DDIM+n]) << 16);
        *(uint2*)((unsigned short*)(ws + WS_WT) + e0) = make_uint2(r0, r1);
        return;
    }
    __shared__ float redG[16][17];
    __shared__ float redC[16][17];
    const int k = tid & 15, g = tid >> 4;
    float pG = 0.f, pC = 0.f;
    for (int i = g*(HDIM/16); i < (g+1)*(HDIM/16); ++i) {
        const float w = W_down[i*DDIM + k];
        pG = fmaf(g1[i], w, pG);
        pC = fmaf(b1[i], w, pC);
    }
    redG[g][k] = pG; redC[g][k] = pC;
    __syncthreads();
    if (tid < 16) {
        float sG = 0.f, sC = 0.f;
        for (int gg = 0; gg < 16; ++gg) { sG += redG[gg][tid]; sC += redC[gg][tid]; }
        ws[WS_G + tid] = sG;
        ws[WS_C + tid] = sC + b_down[tid];
    }
    for (int e = tid; e < MMEM*DDIM; e += 256) {
        const int m = e >> 4, kk = e & 15;
        float sk = b_k[kk], sv = b_v[kk];
        for (int dd = 0; dd < DDIM; ++dd) {
            const float mv = memory[m*DDIM + dd];
            sk = fmaf(mv, W_k[dd*DDIM + kk], sk);
            sv = fmaf(mv, W_v[dd*DDIM + kk], sv);
        }
        ws[WS_KEY + e] = sk;
        ws[WS_VAL + e] = sv;
    }
}

// issue the 4 coalesced float4 loads of (sub-block-local) chunk CC
#define LOADCHUNK(CC, RR)                                                     \
    {                                                                         \
        _Pragma("unroll")                                                     \
        for (int j = 0; j < 4; ++j) {                                         \
            const int r = (j*4 + w4)*4 + q;                                   \
            (RR)[j] = *(const float4*)(x + (size_t)(t0 + r)*HDIM              \
                                       + (hbase + (CC))*64 + sc);             \
        }                                                                     \
    }

// truncate-to-bf16 pack + exact fp32 stats (hi plane only). BB = buffer byte
// base within this sub-block's region.
#define CVTWRITE(RR, BB)                                                      \
    {                                                                         \
        _Pragma("unroll")                                                     \
        for (int j = 0; j < 4; ++j) {                                         \
            const float4 v = (RR)[j];                                         \
            const int r_ = (j*4 + w4)*4 + q;                                  \
            s0a[j] += v.x + v.y + v.z + v.w;                                  \
            s1a[j] = fmaf(v.x,v.x,fmaf(v.y,v.y,fmaf(v.z,v.z,fmaf(v.w,v.w,s1a[j])))); \
            const unsigned ux = __builtin_bit_cast(unsigned, v.x);            \
            const unsigned uy = __builtin_bit_cast(unsigned, v.y);            \
            const unsigned uz = __builtin_bit_cast(unsigned, v.z);            \
            const unsigned uw = __builtin_bit_cast(unsigned, v.w);            \
            const unsigned h01 = (ux >> 16) | (uy & 0xFFFF0000u);             \
            const unsigned h23 = (uz >> 16) | (uw & 0xFFFF0000u);             \
            const int off_ = sbase + (BB) + r_*128 + ((g0 ^ (r_ & 7)))*16 + sub; \
            *(uint2*)(lds + off_) = make_uint2(h01, h23);                     \
        }                                                                     \
    }

// fused, H-split: block = 8 waves = 64 tokens. Two 4-wave sub-blocks each do
// half the H-chunks (own 32KB buffers); partial acc/stats merged via LDS.
// 16 waves/CU (4/SIMD) for latency hiding. Tail + up phase as R17.
__global__ __launch_bounds__(512)
__attribute__((amdgpu_waves_per_eu(4, 4)))
void fused_kernel(
    const float* __restrict__ x, const float* __restrict__ ws,
    const float* __restrict__ g2, const float* __restrict__ b2,
    const float* __restrict__ g3, const float* __restrict__ b3,
    const float* __restrict__ W_up, const float* __restrict__ b_up,
    float* __restrict__ out)
{
    __shared__ __align__(16) char lds[65536];   // 2 sub-blocks x 4 x 8KB
    const int tid  = threadIdx.x;
    const int lane = tid & 63;
    const int w    = tid >> 6;           // wave 0..7
    const int w4   = w & 3;
    const int sb   = w >> 2;             // sub-block 0/1
    const int sbase = sb * 32768;        // LDS byte base
    const int hbase = sb * 6;            // chunk offset (6 chunks each)
    const int t0   = blockIdx.x * 64;

    // staging thread coords
    const int q   = lane >> 4;           // 0..3
    const int sc  = (lane & 15) * 4;     // fp32 col within 64-chunk
    const int g0  = (lane & 15) >> 1;    // granule 0..7
    const int sub = (lane & 1) * 8;      // byte half-granule

    float s0a[4] = {0.f,0.f,0.f,0.f}, s1a[4] = {0.f,0.f,0.f,0.f};
    float4 ldr[3][4];

    LOADCHUNK(0, ldr[0])
    LOADCHUNK(1, ldr[1])
    LOADCHUNK(2, ldr[2])

    CVTWRITE(ldr[0], 0)
    __syncthreads();

    f32x4 acc = {0.f, 0.f, 0.f, 0.f};
    const int fr   = w4*16 + (lane & 15); // x-tile row (token)
    const int frx7 = fr & 7;
    const int rww  = lane & 15;           // WT row (k)
    const int fq   = lane >> 4;           // k-quadrant
    const unsigned short* __restrict__ WTg =
        (const unsigned short*)(ws + WS_WT) + rww*768 + fq*8;

#pragma unroll
    for (int hc = 0; hc < 6; ++hc) {
        const int cb = sbase + (hc & 3) * 8192;
        if (hc + 3 < 6) LOADCHUNK(hc + 3, ldr[hc % 3])
        if (hc + 1 < 6) CVTWRITE(ldr[(hc + 1) % 3], ((hc + 1) & 3) * 8192)
#pragma unroll
        for (int kk = 0; kk < 2; ++kk) {
            const int gx   = kk*4 + fq;
            const int xoff = cb + fr*128 + (gx ^ frx7)*16;
            const bf16x8 ah = *(const bf16x8*)(lds + xoff);
            const bf16x8 bw = *(const bf16x8*)(WTg + (hbase + hc)*64 + kk*32);
            acc = __builtin_amdgcn_mfma_f32_16x16x32_bf16(bw, ah, acc, 0, 0, 0);
        }
        __syncthreads();
    }

    // ---- merge partials + tail ----
    float* trans  = (float*)(lds + 8192);
    float* trans2 = (float*)(lds + 16384);
    float* tr = sb ? trans2 : trans;
    const int tw = w4*16 + (lane & 15);    // block-local token
#pragma unroll
    for (int i = 0; i < 4; ++i)
        tr[tw*19 + fq*4 + i] = acc[i];

#pragma unroll
    for (int m = 1; m <= 8; m <<= 1) {
#pragma unroll
        for (int j = 0; j < 4; ++j) {
            s0a[j] += __shfl_xor(s0a[j], m, 64);
            s1a[j] += __shfl_xor(s1a[j], m, 64);
        }
    }
    if ((lane & 15) == 0) {
#pragma unroll
        for (int j = 0; j < 4; ++j) {
            const int r = (j*4 + w4)*4 + q;
            tr[r*19 + 16] = s0a[j];
            tr[r*19 + 17] = s1a[j];
        }
    }

    // stage KEY/VAL (400 float4) at LDS base
    float* KV = (float*)lds;
    {
        const float4* src = (const float4*)(ws + WS_KEY);
        float4* dst = (float4*)KV;
        if (tid < 400) dst[tid] = src[tid];
    }
    __syncthreads();

    // tail computed by all 8 waves (wave pairs redundant — same inputs)
    const int sg = lane >> 4;            // softmax split group 0..3
    float fA[16];
#pragma unroll
    for (int k = 0; k < 16; ++k) fA[k] = trans[tw*19 + k] + trans2[tw*19 + k];
    const float fS0 = trans[tw*19 + 16] + trans2[tw*19 + 16];
    const float fS1 = trans[tw*19 + 17] + trans2[tw*19 + 17];

    const float inv_h = 1.0f / 768.0f;
    const float mean1 = fS0 * inv_h;
    const float var1 = fmaf(-mean1, mean1, fS1 * inv_h);
    const float rs1 = rsqrtf(var1 + LN_EPS);
    float d[16];
#pragma unroll
    for (int k = 0; k < 16; ++k)
        d[k] = fmaf(rs1, fmaf(-mean1, ws[WS_G + k], fA[k]), ws[WS_C + k]);

    float t0s = 0.f;
#pragma unroll
    for (int k = 0; k < 16; ++k) t0s += d[k];
    const float mean2 = t0s * 0.0625f;
    float t1s = 0.f;
#pragma unroll
    for (int k = 0; k < 16; ++k) { const float c = d[k] - mean2; t1s = fmaf(c, c, t1s); }
    const float rs2 = rsqrtf(t1s * 0.0625f + LN_EPS);
    float qv[16];
#pragma unroll
    for (int k = 0; k < 16; ++k)
        qv[k] = fmaf((d[k] - mean2) * rs2, g2[k], b2[k]);

    // split softmax (no max-sub: |score| << 1): sg covers 13/13/12/12 memories
    const int mm0 = (sg < 2) ? sg*13 : 26 + (sg - 2)*12;
    const int mm1 = mm0 + ((sg < 2) ? 13 : 12);
    float mo[16];
#pragma unroll
    for (int k = 0; k < 16; ++k) mo[k] = 0.f;
    float ssum = 0.f;
#pragma unroll 1
    for (int mm = mm0; mm < mm1; ++mm) {
        float a = 0.f;
#pragma unroll
        for (int k = 0; k < 16; ++k) a = fmaf(qv[k], KV[mm*16 + k], a);
        const float e = __expf(a);
        ssum += e;
#pragma unroll
        for (int k = 0; k < 16; ++k) mo[k] = fmaf(e, KV[800 + mm*16 + k], mo[k]);
    }
    ssum += __shfl_xor(ssum, 16, 64);
    ssum += __shfl_xor(ssum, 32, 64);
#pragma unroll
    for (int k = 0; k < 16; ++k) {
        mo[k] += __shfl_xor(mo[k], 16, 64);
        mo[k] += __shfl_xor(mo[k], 32, 64);
    }
    const float rn = 1.0f / ssum;
#pragma unroll
    for (int k = 0; k < 16; ++k) mo[k] *= rn;

    float u0 = 0.f;
#pragma unroll
    for (int k = 0; k < 16; ++k) u0 += mo[k];
    const float mean3 = u0 * 0.0625f;
    float u1 = 0.f;
#pragma unroll
    for (int k = 0; k < 16; ++k) { const float c = mo[k] - mean3; u1 = fmaf(c, c, u1); }
    const float rs3 = rsqrtf(u1 * 0.0625f + LN_EPS);

    float4 mq;
    if (sg == 0)      mq = make_float4(mo[0],  mo[1],  mo[2],  mo[3]);
    else if (sg == 1) mq = make_float4(mo[4],  mo[5],  mo[6],  mo[7]);
    else if (sg == 2) mq = make_float4(mo[8],  mo[9],  mo[10], mo[11]);
    else              mq = make_float4(mo[12], mo[13], mo[14], mo[15]);
    const float4 gq = *(const float4*)(g3 + sg*4);
    const float4 bq = *(const float4*)(b3 + sg*4);
    float4 stv;
    stv.x = fmaf((mq.x - mean3) * rs3, gq.x, bq.x);
    stv.y = fmaf((mq.y - mean3) * rs3, gq.y, bq.y);
    stv.z = fmaf((mq.z - mean3) * rs3, gq.z, bq.z);
    stv.w = fmaf((mq.w - mean3) * rs3, gq.w, bq.w);

    // park r in LDS [64][20] floats; only sub-block 0 writes (pair duplicates)
    float* r_lds = (float*)(lds + 24576);
    if (sb == 0)
        *(float4*)(r_lds + tw*20 + sg*4) = stv;
    __syncthreads();

    // ---- up phase: 8 waves x 8 tokens x 3 col-groups ----
#pragma unroll 1
    for (int jg = 0; jg < 3; ++jg) {
        const int j0 = jg * 256 + lane * 4;
        float4 wv[16];
#pragma unroll
        for (int k = 0; k < 16; ++k)
            wv[k] = *(const float4*)(W_up + k*HDIM + j0);
        const float4 bu = *(const float4*)(b_up + j0);
#pragma unroll 2
        for (int tt = 0; tt < 8; ++tt) {
            const int tloc = w*8 + tt;
            const float* rt = r_lds + tloc*20;   // uniform addr -> broadcast
            float4 a2 = bu;
#pragma unroll
            for (int k = 0; k < 16; ++k) {
                const float rk = rt[k];
                a2.x = fmaf(rk, wv[k].x, a2.x);
                a2.y = fmaf(rk, wv[k].y, a2.y);
                a2.z = fmaf(rk, wv[k].z, a2.z);
                a2.w = fmaf(rk, wv[k].w, a2.w);
            }
            *(float4*)(out + (size_t)(t0 + tloc) * HDIM + j0) = a2;
        }
    }
}

extern "C" void kernel_launch(void* const* d_in, const int* in_sizes, int n_in,
                              void* d_out, int out_size, void* d_ws, size_t ws_size,
                              hipStream_t stream) {
    const float* x      = (const float*)d_in[0];
    const float* g1     = (const float*)d_in[1];
    const float* b1     = (const float*)d_in[2];
    const float* W_down = (const float*)d_in[3];
    const float* b_down = (const float*)d_in[4];
    const float* g2     = (const float*)d_in[5];
    const float* b2     = (const float*)d_in[6];
    const float* memory = (const float*)d_in[7];
    const float* W_k    = (const float*)d_in[8];
    const float* b_k    = (const float*)d_in[9];
    const float* W_v    = (const float*)d_in[10];
    const float* b_v    = (const float*)d_in[11];
    const float* g3     = (const float*)d_in[12];
    const float* b3     = (const float*)d_in[13];
    const float* W_up   = (const float*)d_in[14];
    const float* b_up   = (const float*)d_in[15];
    float* out = (float*)d_out;
    float* ws  = (float*)d_ws;

    hipLaunchKernelGGL(pre_kernel, dim3(13), dim3(256), 0, stream,
                       g1, b1, W_down, b_down, memory, W_k, b_k, W_v, b_v, ws);
    hipLaunchKernelGGL(fused_kernel, dim3(NTOK/64), dim3(512), 0, stream,
                       x, ws, g2, b2, g3, b3, W_up, b_up, out);
}

// Round 19
// 140.406 us; speedup vs baseline: 2.5506x; 2.5506x over previous
//
#include <hip/hip_runtime.h>
#include <cstdint>

#define LN_EPS 1e-12f
#define NTOK 32768
#define HDIM 768
#define DDIM 16
#define MMEM 50

// ws layout (float offsets)
#define WS_G    0        // 16
#define WS_C    16       // 16 (includes b_down)
#define WS_KEY  32       // 800
#define WS_VAL  832      // 800
#define WS_WT   1632     // 12288 ushorts (bf16 W1^T [16][768]) = 3072 floats

typedef short bf16x8 __attribute__((ext_vector_type(8)));
typedef float f32x4 __attribute__((ext_vector_type(4)));

// bf16 via raw bits (RNE) — for weights
__device__ __forceinline__ unsigned f2bf(float f) {
    const unsigned u = __builtin_bit_cast(unsigned, f);
    return (u + 0x7FFFu + ((u >> 16) & 1u)) >> 16;
}

// 13 blocks: block 0 = G/C + KEY/VAL; blocks 1..12 = WT conversion slices.
__global__ __launch_bounds__(256) void pre_kernel(
    const float* __restrict__ g1, const float* __restrict__ b1,
    const float* __restrict__ W_down, const float* __restrict__ b_down,
    const float* __restrict__ memory, const float* __restrict__ W_k,
    const float* __restrict__ b_k, const float* __restrict__ W_v,
    const float* __restrict__ b_v, float* __restrict__ ws)
{
    const int tid = threadIdx.x;
    const int blk = blockIdx.x;
    if (blk > 0) {
        const int e0 = (blk - 1) * 1024 + tid * 4;
        const int n  = e0 / HDIM;
        const int h  = e0 - n * HDIM;
        const unsigned r0 = f2bf(g1[h+0]*W_down[(h+0)*DDIM+n])
                          | (f2bf(g1[h+1]*W_down[(h+1)*DDIM+n]) << 16);
        const unsigned r1 = f2bf(g1[h+2]*W_down[(h+2)*DDIM+n])
                          | (f2bf(g1[h+3]*W_down[(h+3)*DDIM+n]) << 16);
        *(uint2*)((unsigned short*)(ws + WS_WT) + e0) = make_uint2(r0, r1);
        return;
    }
    __shared__ float redG[16][17];
    __shared__ float redC[16][17];
    const int k = tid & 15, g = tid >> 4;
    float pG = 0.f, pC = 0.f;
    for (int i = g*(HDIM/16); i < (g+1)*(HDIM/16); ++i) {
        const float w = W_down[i*DDIM + k];
        pG = fmaf(g1[i], w, pG);
        pC = fmaf(b1[i], w, pC);
    }
    redG[g][k] = pG; redC[g][k] = pC;
    __syncthreads();
    if (tid < 16) {
        float sG = 0.f, sC = 0.f;
        for (int gg = 0; gg < 16; ++gg) { sG += redG[gg][tid]; sC += redC[gg][tid]; }
        ws[WS_G + tid] = sG;
        ws[WS_C + tid] = sC + b_down[tid];
    }
    for (int e = tid; e < MMEM*DDIM; e += 256) {
        const int m = e >> 4, kk = e & 15;
        float sk = b_k[kk], sv = b_v[kk];
        for (int dd = 0; dd < DDIM; ++dd) {
            const float mv = memory[m*DDIM + dd];
            sk = fmaf(mv, W_k[dd*DDIM + kk], sk);
            sv = fmaf(mv, W_v[dd*DDIM + kk], sv);
        }
        ws[WS_KEY + e] = sk;
        ws[WS_VAL + e] = sv;
    }
}

// issue the 4 coalesced float4 loads of (sub-block-local) chunk CC
// rows r = j*8 + w2*4 + q cover all 32 tokens; cols sc..sc+3 coalesced.
#define LOADCHUNK(CC, RR)                                                     \
    {                                                                         \
        _Pragma("unroll")                                                     \
        for (int j = 0; j < 4; ++j) {                                         \
            const int r = j*8 + w2*4 + q;                                     \
            (RR)[j] = *(const float4*)(x + (size_t)(t0 + r)*HDIM              \
                                       + (hbase + (CC))*64 + sc);             \
        }                                                                     \
    }

// truncate-to-bf16 pack + exact fp32 stats (hi plane only).
#define CVTWRITE(RR, BB)                                                      \
    {                                                                         \
        _Pragma("unroll")                                                     \
        for (int j = 0; j < 4; ++j) {                                         \
            const float4 v = (RR)[j];                                         \
            const int r_ = j*8 + w2*4 + q;                                    \
            s0a[j] += v.x + v.y + v.z + v.w;                                  \
            s1a[j] = fmaf(v.x,v.x,fmaf(v.y,v.y,fmaf(v.z,v.z,fmaf(v.w,v.w,s1a[j])))); \
            const unsigned ux = __builtin_bit_cast(unsigned, v.x);            \
            const unsigned uy = __builtin_bit_cast(unsigned, v.y);            \
            const unsigned uz = __builtin_bit_cast(unsigned, v.z);            \
            const unsigned uw = __builtin_bit_cast(unsigned, v.w);            \
            const unsigned h01 = (ux >> 16) | (uy & 0xFFFF0000u);             \
            const unsigned h23 = (uz >> 16) | (uw & 0xFFFF0000u);             \
            const int off_ = sbase + (BB) + r_*128 + ((g0 ^ (r_ & 7)))*16 + sub; \
            *(uint2*)(lds + off_) = make_uint2(h01, h23);                     \
        }                                                                     \
    }

// fused: block = 4 waves = 32 tokens, K-split 2-way (waves {0,1}=chunks 0-5,
// waves {2,3}=chunks 6-11). 1024 blocks -> 4 blocks/CU = 16 waves/CU.
// Up phase acc-batch (no wv[16] array) keeps peak VGPR low -> no spill.
__global__ __launch_bounds__(256) void fused_kernel(
    const float* __restrict__ x, const float* __restrict__ ws,
    const float* __restrict__ g2, const float* __restrict__ b2,
    const float* __restrict__ g3, const float* __restrict__ b3,
    const float* __restrict__ W_up, const float* __restrict__ b_up,
    float* __restrict__ out)
{
    __shared__ __align__(16) char lds[32768];   // 2 sub-blocks x 4 x 4KB
    const int tid  = threadIdx.x;
    const int lane = tid & 63;
    const int w    = tid >> 6;           // wave 0..3
    const int w2   = w & 1;              // wave within sub-block
    const int sb   = w >> 1;             // sub-block 0/1 (K-half)
    const int sbase = sb * 16384;        // LDS byte base of x-bufs
    const int hbase = sb * 6;            // first chunk of this K-half
    const int t0   = blockIdx.x * 32;

    // staging thread coords
    const int q   = lane >> 4;           // 0..3
    const int sc  = (lane & 15) * 4;     // fp32 col within 64-chunk
    const int g0  = (lane & 15) >> 1;    // granule 0..7
    const int sub = (lane & 1) * 8;      // byte half-granule

    float s0a[4] = {0.f,0.f,0.f,0.f}, s1a[4] = {0.f,0.f,0.f,0.f};
    float4 ldr[2][4];

    LOADCHUNK(0, ldr[0])
    LOADCHUNK(1, ldr[1])

    CVTWRITE(ldr[0], 0)
    __syncthreads();

    f32x4 acc = {0.f, 0.f, 0.f, 0.f};
    const int fr   = w2*16 + (lane & 15); // x-tile row (token)
    const int frx7 = fr & 7;
    const int rww  = lane & 15;           // WT row (k)
    const int fq   = lane >> 4;           // k-quadrant
    const unsigned short* __restrict__ WTg =
        (const unsigned short*)(ws + WS_WT) + rww*768 + fq*8;

#pragma unroll
    for (int hc = 0; hc < 6; ++hc) {
        const int cb = sbase + (hc & 3) * 4096;
        if (hc + 2 < 6) LOADCHUNK(hc + 2, ldr[hc & 1])
        if (hc + 1 < 6) CVTWRITE(ldr[(hc + 1) & 1], ((hc + 1) & 3) * 4096)
#pragma unroll
        for (int kk = 0; kk < 2; ++kk) {
            const int gx   = kk*4 + fq;
            const int xoff = cb + fr*128 + (gx ^ frx7)*16;
            const bf16x8 ah = *(const bf16x8*)(lds + xoff);
            const bf16x8 bw = *(const bf16x8*)(WTg + (hbase + hc)*64 + kk*32);
            acc = __builtin_amdgcn_mfma_f32_16x16x32_bf16(bw, ah, acc, 0, 0, 0);
        }
        __syncthreads();
    }

    // ---- merge partials + tail (x-bufs dead behind the last barrier) ----
    // LDS map now: KV @0 (6.4KB), trans @8192, trans2 @12288, r_lds @16384
    float* trans  = (float*)(lds + 8192);
    float* trans2 = (float*)(lds + 12288);
    float* tr = sb ? trans2 : trans;
    const int tw = w2*16 + (lane & 15);    // block-local token 0..31
#pragma unroll
    for (int i = 0; i < 4; ++i)
        tr[tw*19 + fq*4 + i] = acc[i];

#pragma unroll
    for (int m = 1; m <= 8; m <<= 1) {
#pragma unroll
        for (int j = 0; j < 4; ++j) {
            s0a[j] += __shfl_xor(s0a[j], m, 64);
            s1a[j] += __shfl_xor(s1a[j], m, 64);
        }
    }
    if ((lane & 15) == 0) {
#pragma unroll
        for (int j = 0; j < 4; ++j) {
            const int r = j*8 + w2*4 + q;
            tr[r*19 + 16] = s0a[j];
            tr[r*19 + 17] = s1a[j];
        }
    }

    // stage KEY/VAL (400 float4) at LDS base
    float* KV = (float*)lds;
    {
        const float4* src = (const float4*)(ws + WS_KEY);
        float4* dst = (float4*)KV;
        dst[tid] = src[tid];
        if (tid < 144) dst[256 + tid] = src[256 + tid];
    }
    __syncthreads();

    // tail computed by all 4 waves (wave pairs redundant — same inputs)
    const int sg = lane >> 4;            // softmax split group 0..3
    float fA[16];
#pragma unroll
    for (int k = 0; k < 16; ++k) fA[k] = trans[tw*19 + k] + trans2[tw*19 + k];
    const float fS0 = trans[tw*19 + 16] + trans2[tw*19 + 16];
    const float fS1 = trans[tw*19 + 17] + trans2[tw*19 + 17];

    const float inv_h = 1.0f / 768.0f;
    const float mean1 = fS0 * inv_h;
    const float var1 = fmaf(-mean1, mean1, fS1 * inv_h);
    const float rs1 = rsqrtf(var1 + LN_EPS);
    float d[16];
#pragma unroll
    for (int k = 0; k < 16; ++k)
        d[k] = fmaf(rs1, fmaf(-mean1, ws[WS_G + k], fA[k]), ws[WS_C + k]);

    float t0s = 0.f;
#pragma unroll
    for (int k = 0; k < 16; ++k) t0s += d[k];
    const float mean2 = t0s * 0.0625f;
    float t1s = 0.f;
#pragma unroll
    for (int k = 0; k < 16; ++k) { const float c = d[k] - mean2; t1s = fmaf(c, c, t1s); }
    const float rs2 = rsqrtf(t1s * 0.0625f + LN_EPS);
    float qv[16];
#pragma unroll
    for (int k = 0; k < 16; ++k)
        qv[k] = fmaf((d[k] - mean2) * rs2, g2[k], b2[k]);

    // split softmax (no max-sub: |score| << 1): sg covers 13/13/12/12 memories
    const int mm0 = (sg < 2) ? sg*13 : 26 + (sg - 2)*12;
    const int mm1 = mm0 + ((sg < 2) ? 13 : 12);
    float mo[16];
#pragma unroll
    for (int k = 0; k < 16; ++k) mo[k] = 0.f;
    float ssum = 0.f;
#pragma unroll 1
    for (int mm = mm0; mm < mm1; ++mm) {
        float a = 0.f;
#pragma unroll
        for (int k = 0; k < 16; ++k) a = fmaf(qv[k], KV[mm*16 + k], a);
        const float e = __expf(a);
        ssum += e;
#pragma unroll
        for (int k = 0; k < 16; ++k) mo[k] = fmaf(e, KV[800 + mm*16 + k], mo[k]);
    }
    ssum += __shfl_xor(ssum, 16, 64);
    ssum += __shfl_xor(ssum, 32, 64);
#pragma unroll
    for (int k = 0; k < 16; ++k) {
        mo[k] += __shfl_xor(mo[k], 16, 64);
        mo[k] += __shfl_xor(mo[k], 32, 64);
    }
    const float rn = 1.0f / ssum;
#pragma unroll
    for (int k = 0; k < 16; ++k) mo[k] *= rn;

    float u0 = 0.f;
#pragma unroll
    for (int k = 0; k < 16; ++k) u0 += mo[k];
    const float mean3 = u0 * 0.0625f;
    float u1 = 0.f;
#pragma unroll
    for (int k = 0; k < 16; ++k) { const float c = mo[k] - mean3; u1 = fmaf(c, c, u1); }
    const float rs3 = rsqrtf(u1 * 0.0625f + LN_EPS);

    float4 mq;
    if (sg == 0)      mq = make_float4(mo[0],  mo[1],  mo[2],  mo[3]);
    else if (sg == 1) mq = make_float4(mo[4],  mo[5],  mo[6],  mo[7]);
    else if (sg == 2) mq = make_float4(mo[8],  mo[9],  mo[10], mo[11]);
    else              mq = make_float4(mo[12], mo[13], mo[14], mo[15]);
    const float4 gq = *(const float4*)(g3 + sg*4);
    const float4 bq = *(const float4*)(b3 + sg*4);
    float4 stv;
    stv.x = fmaf((mq.x - mean3) * rs3, gq.x, bq.x);
    stv.y = fmaf((mq.y - mean3) * rs3, gq.y, bq.y);
    stv.z = fmaf((mq.z - mean3) * rs3, gq.z, bq.z);
    stv.w = fmaf((mq.w - mean3) * rs3, gq.w, bq.w);

    // park r in LDS [32][20] floats; only sub-block 0 writes (pair duplicates)
    float* r_lds = (float*)(lds + 16384);
    if (sb == 0)
        *(float4*)(r_lds + tw*20 + sg*4) = stv;
    __syncthreads();

    // ---- up phase, acc-batch: wave w owns 8 tokens; per col-group, loop k
    // reloading one wv4 per k (no wv[16] -> low VGPR). ----
#pragma unroll 1
    for (int jg = 0; jg < 3; ++jg) {
        const int j0 = jg * 256 + lane * 4;
        const float4 bu = *(const float4*)(b_up + j0);
        float4 a2[8];
#pragma unroll
        for (int tt = 0; tt < 8; ++tt) a2[tt] = bu;
#pragma unroll
        for (int k = 0; k < 16; ++k) {
            const float4 wv = *(const float4*)(W_up + k*HDIM + j0);
#pragma unroll
            for (int tt = 0; tt < 8; ++tt) {
                const float rk = r_lds[(w*8 + tt)*20 + k];  // uniform -> broadcast
                a2[tt].x = fmaf(rk, wv.x, a2[tt].x);
                a2[tt].y = fmaf(rk, wv.y, a2[tt].y);
                a2[tt].z = fmaf(rk, wv.z, a2[tt].z);
                a2[tt].w = fmaf(rk, wv.w, a2[tt].w);
            }
        }
#pragma unroll
        for (int tt = 0; tt < 8; ++tt)
            *(float4*)(out + (size_t)(t0 + w*8 + tt) * HDIM + j0) = a2[tt];
    }
}

extern "C" void kernel_launch(void* const* d_in, const int* in_sizes, int n_in,
                              void* d_out, int out_size, void* d_ws, size_t ws_size,
                              hipStream_t stream) {
    const float* x      = (const float*)d_in[0];
    const float* g1     = (const float*)d_in[1];
    const float* b1     = (const float*)d_in[2];
    const float* W_down = (const float*)d_in[3];
    const float* b_down = (const float*)d_in[4];
    const float* g2     = (const float*)d_in[5];
    const float* b2     = (const float*)d_in[6];
    const float* memory = (const float*)d_in[7];
    const float* W_k    = (const float*)d_in[8];
    const float* b_k    = (const float*)d_in[9];
    const float* W_v    = (const float*)d_in[10];
    const float* b_v    = (const float*)d_in[11];
    const float* g3     = (const float*)d_in[12];
    const float* b3     = (const float*)d_in[13];
    const float* W_up   = (const float*)d_in[14];
    const float* b_up   = (const float*)d_in[15];
    float* out = (float*)d_out;
    float* ws  = (float*)d_ws;

    hipLaunchKernelGGL(pre_kernel, dim3(13), dim3(256), 0, stream,
                       g1, b1, W_down, b_down, memory, W_k, b_k, W_v, b_v, ws);
    hipLaunchKernelGGL(fused_kernel, dim3(NTOK/32), dim3(256), 0, stream,
                       x, ws, g2, b2, g3, b3, W_up, b_up, out);
}

// Round 20
// 70.623 us; speedup vs baseline: 5.0710x; 1.9881x over previous
//
#include <hip/hip_runtime.h>
#include <cstdint>

#define LN_EPS 1e-12f
#define NTOK 32768
#define HDIM 768
#define DDIM 16
#define MMEM 50

// ws layout (float offsets)
#define WS_G    0        // 16
#define WS_C    16       // 16 (includes b_down)
#define WS_KEY  32       // 800
#define WS_VAL  832      // 800
#define WS_WT   1632     // 12288 ushorts (bf16 W1^T [16][768]) = 3072 floats

typedef short bf16x8 __attribute__((ext_vector_type(8)));
typedef float f32x4 __attribute__((ext_vector_type(4)));

// bf16 via raw bits (RNE) — for weights
__device__ __forceinline__ unsigned f2bf(float f) {
    const unsigned u = __builtin_bit_cast(unsigned, f);
    return (u + 0x7FFFu + ((u >> 16) & 1u)) >> 16;
}

// 13 blocks: block 0 = G/C + KEY/VAL; blocks 1..12 = WT conversion slices.
__global__ __launch_bounds__(256) void pre_kernel(
    const float* __restrict__ g1, const float* __restrict__ b1,
    const float* __restrict__ W_down, const float* __restrict__ b_down,
    const float* __restrict__ memory, const float* __restrict__ W_k,
    const float* __restrict__ b_k, const float* __restrict__ W_v,
    const float* __restrict__ b_v, float* __restrict__ ws)
{
    const int tid = threadIdx.x;
    const int blk = blockIdx.x;
    if (blk > 0) {
        const int e0 = (blk - 1) * 1024 + tid * 4;
        const int n  = e0 / HDIM;
        const int h  = e0 - n * HDIM;
        const unsigned r0 = f2bf(g1[h+0]*W_down[(h+0)*DDIM+n])
                          | (f2bf(g1[h+1]*W_down[(h+1)*DDIM+n]) << 16);
        const unsigned r1 = f2bf(g1[h+2]*W_down[(h+2)*DDIM+n])
                          | (f2bf(g1[h+3]*W_down[(h+3)*DDIM+n]) << 16);
        *(uint2*)((unsigned short*)(ws + WS_WT) + e0) = make_uint2(r0, r1);
        return;
    }
    __shared__ float redG[16][17];
    __shared__ float redC[16][17];
    const int k = tid & 15, g = tid >> 4;
    float pG = 0.f, pC = 0.f;
    for (int i = g*(HDIM/16); i < (g+1)*(HDIM/16); ++i) {
        const float w = W_down[i*DDIM + k];
        pG = fmaf(g1[i], w, pG);
        pC = fmaf(b1[i], w, pC);
    }
    redG[g][k] = pG; redC[g][k] = pC;
    __syncthreads();
    if (tid < 16) {
        float sG = 0.f, sC = 0.f;
        for (int gg = 0; gg < 16; ++gg) { sG += redG[gg][tid]; sC += redC[gg][tid]; }
        ws[WS_G + tid] = sG;
        ws[WS_C + tid] = sC + b_down[tid];
    }
    for (int e = tid; e < MMEM*DDIM; e += 256) {
        const int m = e >> 4, kk = e & 15;
        float sk = b_k[kk], sv = b_v[kk];
        for (int dd = 0; dd < DDIM; ++dd) {
            const float mv = memory[m*DDIM + dd];
            sk = fmaf(mv, W_k[dd*DDIM + kk], sk);
            sv = fmaf(mv, W_v[dd*DDIM + kk], sv);
        }
        ws[WS_KEY + e] = sk;
        ws[WS_VAL + e] = sv;
    }
}

// issue the 4 coalesced float4 loads of (sub-block-local) chunk CC
// rows r = j*8 + w2*4 + q cover all 32 tokens; cols sc..sc+3 coalesced.
#define LOADCHUNK(CC, RR)                                                     \
    {                                                                         \
        _Pragma("unroll")                                                     \
        for (int j = 0; j < 4; ++j) {                                         \
            const int r = j*8 + w2*4 + q;                                     \
            (RR)[j] = *(const float4*)(x + (size_t)(t0 + r)*HDIM              \
                                       + (hbase + (CC))*64 + sc);             \
        }                                                                     \
    }

// truncate-to-bf16 pack + exact fp32 stats (hi plane only).
#define CVTWRITE(RR, BB)                                                      \
    {                                                                         \
        _Pragma("unroll")                                                     \
        for (int j = 0; j < 4; ++j) {                                         \
            const float4 v = (RR)[j];                                         \
            const int r_ = j*8 + w2*4 + q;                                    \
            s0a[j] += v.x + v.y + v.z + v.w;                                  \
            s1a[j] = fmaf(v.x,v.x,fmaf(v.y,v.y,fmaf(v.z,v.z,fmaf(v.w,v.w,s1a[j])))); \
            const unsigned ux = __builtin_bit_cast(unsigned, v.x);            \
            const unsigned uy = __builtin_bit_cast(unsigned, v.y);            \
            const unsigned uz = __builtin_bit_cast(unsigned, v.z);            \
            const unsigned uw = __builtin_bit_cast(unsigned, v.w);            \
            const unsigned h01 = (ux >> 16) | (uy & 0xFFFF0000u);             \
            const unsigned h23 = (uz >> 16) | (uw & 0xFFFF0000u);             \
            const int off_ = sbase + (BB) + r_*128 + ((g0 ^ (r_ & 7)))*16 + sub; \
            *(uint2*)(lds + off_) = make_uint2(h01, h23);                     \
        }                                                                     \
    }

// fused: block = 4 waves = 32 tokens, K-split 2-way (waves {0,1}=chunks 0-5,
// waves {2,3}=chunks 6-11). 1024 blocks -> 4 blocks/CU = 16 waves/CU.
// Up phase = R17's verified wv[16] form (116 VGPR), 8 tokens/wave.
__global__ __launch_bounds__(256) void fused_kernel(
    const float* __restrict__ x, const float* __restrict__ ws,
    const float* __restrict__ g2, const float* __restrict__ b2,
    const float* __restrict__ g3, const float* __restrict__ b3,
    const float* __restrict__ W_up, const float* __restrict__ b_up,
    float* __restrict__ out)
{
    __shared__ __align__(16) char lds[32768];   // 2 sub-blocks x 4 x 4KB
    const int tid  = threadIdx.x;
    const int lane = tid & 63;
    const int w    = tid >> 6;           // wave 0..3
    const int w2   = w & 1;              // wave within sub-block
    const int sb   = w >> 1;             // sub-block 0/1 (K-half)
    const int sbase = sb * 16384;        // LDS byte base of x-bufs
    const int hbase = sb * 6;            // first chunk of this K-half
    const int t0   = blockIdx.x * 32;

    // staging thread coords
    const int q   = lane >> 4;           // 0..3
    const int sc  = (lane & 15) * 4;     // fp32 col within 64-chunk
    const int g0  = (lane & 15) >> 1;    // granule 0..7
    const int sub = (lane & 1) * 8;      // byte half-granule

    float s0a[4] = {0.f,0.f,0.f,0.f}, s1a[4] = {0.f,0.f,0.f,0.f};
    float4 ldr[2][4];

    LOADCHUNK(0, ldr[0])
    LOADCHUNK(1, ldr[1])

    CVTWRITE(ldr[0], 0)
    __syncthreads();

    f32x4 acc = {0.f, 0.f, 0.f, 0.f};
    const int fr   = w2*16 + (lane & 15); // x-tile row (token)
    const int frx7 = fr & 7;
    const int rww  = lane & 15;           // WT row (k)
    const int fq   = lane >> 4;           // k-quadrant
    const unsigned short* __restrict__ WTg =
        (const unsigned short*)(ws + WS_WT) + rww*768 + fq*8;

#pragma unroll
    for (int hc = 0; hc < 6; ++hc) {
        const int cb = sbase + (hc & 3) * 4096;
        if (hc + 2 < 6) LOADCHUNK(hc + 2, ldr[hc & 1])
        if (hc + 1 < 6) CVTWRITE(ldr[(hc + 1) & 1], ((hc + 1) & 3) * 4096)
#pragma unroll
        for (int kk = 0; kk < 2; ++kk) {
            const int gx   = kk*4 + fq;
            const int xoff = cb + fr*128 + (gx ^ frx7)*16;
            const bf16x8 ah = *(const bf16x8*)(lds + xoff);
            const bf16x8 bw = *(const bf16x8*)(WTg + (hbase + hc)*64 + kk*32);
            acc = __builtin_amdgcn_mfma_f32_16x16x32_bf16(bw, ah, acc, 0, 0, 0);
        }
        __syncthreads();
    }

    // ---- merge partials + tail (x-bufs dead behind the last barrier) ----
    // LDS map: KV @0 (6.4KB), trans @8192, trans2 @12288, r_lds @16384
    float* trans  = (float*)(lds + 8192);
    float* trans2 = (float*)(lds + 12288);
    float* tr = sb ? trans2 : trans;
    const int tw = w2*16 + (lane & 15);    // block-local token 0..31
#pragma unroll
    for (int i = 0; i < 4; ++i)
        tr[tw*19 + fq*4 + i] = acc[i];

#pragma unroll
    for (int m = 1; m <= 8; m <<= 1) {
#pragma unroll
        for (int j = 0; j < 4; ++j) {
            s0a[j] += __shfl_xor(s0a[j], m, 64);
            s1a[j] += __shfl_xor(s1a[j], m, 64);
        }
    }
    if ((lane & 15) == 0) {
#pragma unroll
        for (int j = 0; j < 4; ++j) {
            const int r = j*8 + w2*4 + q;
            tr[r*19 + 16] = s0a[j];
            tr[r*19 + 17] = s1a[j];
        }
    }

    // stage KEY/VAL (400 float4) at LDS base
    float* KV = (float*)lds;
    {
        const float4* src = (const float4*)(ws + WS_KEY);
        float4* dst = (float4*)KV;
        dst[tid] = src[tid];
        if (tid < 144) dst[256 + tid] = src[256 + tid];
    }
    __syncthreads();

    // tail computed by all 4 waves (wave pairs redundant — same inputs)
    const int sg = lane >> 4;            // softmax split group 0..3
    float fA[16];
#pragma unroll
    for (int k = 0; k < 16; ++k) fA[k] = trans[tw*19 + k] + trans2[tw*19 + k];
    const float fS0 = trans[tw*19 + 16] + trans2[tw*19 + 16];
    const float fS1 = trans[tw*19 + 17] + trans2[tw*19 + 17];

    const float inv_h = 1.0f / 768.0f;
    const float mean1 = fS0 * inv_h;
    const float var1 = fmaf(-mean1, mean1, fS1 * inv_h);
    const float rs1 = rsqrtf(var1 + LN_EPS);
    float d[16];
#pragma unroll
    for (int k = 0; k < 16; ++k)
        d[k] = fmaf(rs1, fmaf(-mean1, ws[WS_G + k], fA[k]), ws[WS_C + k]);

    float t0s = 0.f;
#pragma unroll
    for (int k = 0; k < 16; ++k) t0s += d[k];
    const float mean2 = t0s * 0.0625f;
    float t1s = 0.f;
#pragma unroll
    for (int k = 0; k < 16; ++k) { const float c = d[k] - mean2; t1s = fmaf(c, c, t1s); }
    const float rs2 = rsqrtf(t1s * 0.0625f + LN_EPS);
    float qv[16];
#pragma unroll
    for (int k = 0; k < 16; ++k)
        qv[k] = fmaf((d[k] - mean2) * rs2, g2[k], b2[k]);

    // split softmax (no max-sub: |score| << 1): sg covers 13/13/12/12 memories
    const int mm0 = (sg < 2) ? sg*13 : 26 + (sg - 2)*12;
    const int mm1 = mm0 + ((sg < 2) ? 13 : 12);
    float mo[16];
#pragma unroll
    for (int k = 0; k < 16; ++k) mo[k] = 0.f;
    float ssum = 0.f;
#pragma unroll 1
    for (int mm = mm0; mm < mm1; ++mm) {
        float a = 0.f;
#pragma unroll
        for (int k = 0; k < 16; ++k) a = fmaf(qv[k], KV[mm*16 + k], a);
        const float e = __expf(a);
        ssum += e;
#pragma unroll
        for (int k = 0; k < 16; ++k) mo[k] = fmaf(e, KV[800 + mm*16 + k], mo[k]);
    }
    ssum += __shfl_xor(ssum, 16, 64);
    ssum += __shfl_xor(ssum, 32, 64);
#pragma unroll
    for (int k = 0; k < 16; ++k) {
        mo[k] += __shfl_xor(mo[k], 16, 64);
        mo[k] += __shfl_xor(mo[k], 32, 64);
    }
    const float rn = 1.0f / ssum;
#pragma unroll
    for (int k = 0; k < 16; ++k) mo[k] *= rn;

    float u0 = 0.f;
#pragma unroll
    for (int k = 0; k < 16; ++k) u0 += mo[k];
    const float mean3 = u0 * 0.0625f;
    float u1 = 0.f;
#pragma unroll
    for (int k = 0; k < 16; ++k) { const float c = mo[k] - mean3; u1 = fmaf(c, c, u1); }
    const float rs3 = rsqrtf(u1 * 0.0625f + LN_EPS);

    float4 mq;
    if (sg == 0)      mq = make_float4(mo[0],  mo[1],  mo[2],  mo[3]);
    else if (sg == 1) mq = make_float4(mo[4],  mo[5],  mo[6],  mo[7]);
    else if (sg == 2) mq = make_float4(mo[8],  mo[9],  mo[10], mo[11]);
    else              mq = make_float4(mo[12], mo[13], mo[14], mo[15]);
    const float4 gq = *(const float4*)(g3 + sg*4);
    const float4 bq = *(const float4*)(b3 + sg*4);
    float4 stv;
    stv.x = fmaf((mq.x - mean3) * rs3, gq.x, bq.x);
    stv.y = fmaf((mq.y - mean3) * rs3, gq.y, bq.y);
    stv.z = fmaf((mq.z - mean3) * rs3, gq.z, bq.z);
    stv.w = fmaf((mq.w - mean3) * rs3, gq.w, bq.w);

    // park r in LDS [32][20] floats; only sub-block 0 writes (pair duplicates)
    float* r_lds = (float*)(lds + 16384);
    if (sb == 0)
        *(float4*)(r_lds + tw*20 + sg*4) = stv;
    __syncthreads();

    // ---- up phase (R17 form): wave w covers 8 tokens x 768 cols, wv[16] ----
#pragma unroll 1
    for (int jg = 0; jg < 3; ++jg) {
        const int j0 = jg * 256 + lane * 4;
        float4 wv[16];
#pragma unroll
        for (int k = 0; k < 16; ++k)
            wv[k] = *(const float4*)(W_up + k*HDIM + j0);
        const float4 bu = *(const float4*)(b_up + j0);
#pragma unroll 2
        for (int tt = 0; tt < 8; ++tt) {
            const int tloc = w*8 + tt;
            const float* rt = r_lds + tloc*20;   // uniform addr -> broadcast
            float4 a2 = bu;
#pragma unroll
            for (int k = 0; k < 16; ++k) {
                const float rk = rt[k];
                a2.x = fmaf(rk, wv[k].x, a2.x);
                a2.y = fmaf(rk, wv[k].y, a2.y);
                a2.z = fmaf(rk, wv[k].z, a2.z);
                a2.w = fmaf(rk, wv[k].w, a2.w);
            }
            *(float4*)(out + (size_t)(t0 + tloc) * HDIM + j0) = a2;
        }
    }
}

extern "C" void kernel_launch(void* const* d_in, const int* in_sizes, int n_in,
                              void* d_out, int out_size, void* d_ws, size_t ws_size,
                              hipStream_t stream) {
    const float* x      = (const float*)d_in[0];
    const float* g1     = (const float*)d_in[1];
    const float* b1     = (const float*)d_in[2];
    const float* W_down = (const float*)d_in[3];
    const float* b_down = (const float*)d_in[4];
    const float* g2     = (const float*)d_in[5];
    const float* b2     = (const float*)d_in[6];
    const float* memory = (const float*)d_in[7];
    const float* W_k    = (const float*)d_in[8];
    const float* b_k    = (const float*)d_in[9];
    const float* W_v    = (const float*)d_in[10];
    const float* b_v    = (const float*)d_in[11];
    const float* g3     = (const float*)d_in[12];
    const float* b3     = (const float*)d_in[13];
    const float* W_up   = (const float*)d_in[14];
    const float* b_up   = (const float*)d_in[15];
    float* out = (float*)d_out;
    float* ws  = (float*)d_ws;

    hipLaunchKernelGGL(pre_kernel, dim3(13), dim3(256), 0, stream,
                       g1, b1, W_down, b_down, memory, W_k, b_k, W_v, b_v, ws);
    hipLaunchKernelGGL(fused_kernel, dim3(NTOK/32), dim3(256), 0, stream,
                       x, ws, g2, b2, g3, b3, W_up, b_up, out);
}

// Round 21
// 66.133 us; speedup vs baseline: 5.4152x; 1.0679x over previous
//
#include <hip/hip_runtime.h>
#include <cstdint>

#define LN_EPS 1e-12f
#define NTOK 32768
#define HDIM 768
#define DDIM 16
#define MMEM 50

// ws layout (float offsets)
#define WS_G    0        // 16
#define WS_C    16       // 16 (includes b_down)
#define WS_KEY  32       // 800
#define WS_VAL  832      // 800
#define WS_WT   1632     // 12288 ushorts (bf16 W1^T [16][768]) = 3072 floats

typedef short bf16x8 __attribute__((ext_vector_type(8)));
typedef float f32x4 __attribute__((ext_vector_type(4)));

// bf16 via raw bits (RNE) — for weights
__device__ __forceinline__ unsigned f2bf(float f) {
    const unsigned u = __builtin_bit_cast(unsigned, f);
    return (u + 0x7FFFu + ((u >> 16) & 1u)) >> 16;
}

// 13 blocks: block 0 = G/C + KEY/VAL; blocks 1..12 = WT conversion slices.
__global__ __launch_bounds__(256) void pre_kernel(
    const float* __restrict__ g1, const float* __restrict__ b1,
    const float* __restrict__ W_down, const float* __restrict__ b_down,
    const float* __restrict__ memory, const float* __restrict__ W_k,
    const float* __restrict__ b_k, const float* __restrict__ W_v,
    const float* __restrict__ b_v, float* __restrict__ ws)
{
    const int tid = threadIdx.x;
    const int blk = blockIdx.x;
    if (blk > 0) {
        const int e0 = (blk - 1) * 1024 + tid * 4;
        const int n  = e0 / HDIM;
        const int h  = e0 - n * HDIM;
        const unsigned r0 = f2bf(g1[h+0]*W_down[(h+0)*DDIM+n])
                          | (f2bf(g1[h+1]*W_down[(h+1)*DDIM+n]) << 16);
        const unsigned r1 = f2bf(g1[h+2]*W_down[(h+2)*DDIM+n])
                          | (f2bf(g1[h+3]*W_down[(h+3)*DDIM+n]) << 16);
        *(uint2*)((unsigned short*)(ws + WS_WT) + e0) = make_uint2(r0, r1);
        return;
    }
    __shared__ float redG[16][17];
    __shared__ float redC[16][17];
    const int k = tid & 15, g = tid >> 4;
    float pG = 0.f, pC = 0.f;
    for (int i = g*(HDIM/16); i < (g+1)*(HDIM/16); ++i) {
        const float w = W_down[i*DDIM + k];
        pG = fmaf(g1[i], w, pG);
        pC = fmaf(b1[i], w, pC);
    }
    redG[g][k] = pG; redC[g][k] = pC;
    __syncthreads();
    if (tid < 16) {
        float sG = 0.f, sC = 0.f;
        for (int gg = 0; gg < 16; ++gg) { sG += redG[gg][tid]; sC += redC[gg][tid]; }
        ws[WS_G + tid] = sG;
        ws[WS_C + tid] = sC + b_down[tid];
    }
    for (int e = tid; e < MMEM*DDIM; e += 256) {
        const int m = e >> 4, kk = e & 15;
        float sk = b_k[kk], sv = b_v[kk];
        for (int dd = 0; dd < DDIM; ++dd) {
            const float mv = memory[m*DDIM + dd];
            sk = fmaf(mv, W_k[dd*DDIM + kk], sk);
            sv = fmaf(mv, W_v[dd*DDIM + kk], sv);
        }
        ws[WS_KEY + e] = sk;
        ws[WS_VAL + e] = sv;
    }
}

// per-wave staging: 4 coalesced float4 loads of chunk CC of this wave's
// 16-token tile. Row lr=lane>>2, floats j*16 + lc*4 (64B/row per instr).
#define LOADCHUNK(CC, RR)                                                     \
    {                                                                         \
        _Pragma("unroll")                                                     \
        for (int j = 0; j < 4; ++j)                                           \
            (RR)[j] = *(const float4*)(x + (size_t)(tok0 + lr)*HDIM           \
                                       + (hbase + (CC))*64 + j*16 + lc*4);    \
    }

// truncate-to-bf16 pack + exact fp32 stats into this wave's private buffer.
#define CVTWRITE(RR)                                                          \
    {                                                                         \
        _Pragma("unroll")                                                     \
        for (int j = 0; j < 4; ++j) {                                         \
            const float4 v = (RR)[j];                                         \
            s0 += v.x + v.y + v.z + v.w;                                      \
            s1 = fmaf(v.x,v.x,fmaf(v.y,v.y,fmaf(v.z,v.z,fmaf(v.w,v.w,s1)))); \
            const unsigned ux = __builtin_bit_cast(unsigned, v.x);            \
            const unsigned uy = __builtin_bit_cast(unsigned, v.y);            \
            const unsigned uz = __builtin_bit_cast(unsigned, v.z);            \
            const unsigned uw = __builtin_bit_cast(unsigned, v.w);            \
            const unsigned h01 = (ux >> 16) | (uy & 0xFFFF0000u);             \
            const unsigned h23 = (uz >> 16) | (uw & 0xFFFF0000u);             \
            const int col4 = j*4 + lc;                                        \
            const int gg   = col4 >> 1;                                       \
            const int off_ = wbase + lr*128 + ((gg ^ (lr & 7)))*16            \
                           + (col4 & 1)*8;                                    \
            *(uint2*)(lds + off_) = make_uint2(h01, h23);                     \
        }                                                                     \
    }

// fused, barrier-free waves: block = 4 waves = 32 tokens. Wave pair p shares
// 16 tokens, split H (6 chunks each) with PRIVATE single 4KB LDS buffers
// (same-wave ds ordering -> no staging barriers). ONE __syncthreads (partial
// merge + KV). Tail per-wave, r in pair LDS (self-written), up = wv[16] form.
__global__ __launch_bounds__(256) void fused_kernel(
    const float* __restrict__ x, const float* __restrict__ ws,
    const float* __restrict__ g2, const float* __restrict__ b2,
    const float* __restrict__ g3, const float* __restrict__ b3,
    const float* __restrict__ W_up, const float* __restrict__ b_up,
    float* __restrict__ out)
{
    __shared__ __align__(16) char lds[30208];
    // map: xbuf 4x4KB @0 | KV 6.4KB @16384 | trans 4x304f @22784 | r 2x320f @27648
    const int tid  = threadIdx.x;
    const int lane = tid & 63;
    const int w    = tid >> 6;           // wave 0..3
    const int p    = w >> 1;             // pair 0/1
    const int sb   = w & 1;              // K-half within pair
    const int wbase = w * 4096;          // private x-buf
    const int hbase = sb * 6;            // first chunk of this K-half
    const int t0   = blockIdx.x * 32;
    const int tok0 = t0 + p * 16;        // pair's first token

    const int lr = lane >> 2;            // staging row 0..15
    const int lc = lane & 3;             // staging col quad

    float s0 = 0.f, s1 = 0.f;
    float4 ldr[2][4];

    LOADCHUNK(0, ldr[0])
    LOADCHUNK(1, ldr[1])

    // stage KV (visibility needed only after the single barrier below)
    float* KV = (float*)(lds + 16384);
    {
        const float4* src = (const float4*)(ws + WS_KEY);
        float4* dst = (float4*)KV;
        dst[tid] = src[tid];
        if (tid < 144) dst[256 + tid] = src[256 + tid];
    }

    CVTWRITE(ldr[0])

    f32x4 acc = {0.f, 0.f, 0.f, 0.f};
    const int fr   = lane & 15;          // MFMA x-row (token within pair)
    const int frx7 = fr & 7;
    const int fq   = lane >> 4;          // k-quadrant
    const unsigned short* __restrict__ WTg =
        (const unsigned short*)(ws + WS_WT) + (lane & 15)*768 + fq*8;

#pragma unroll
    for (int hc = 0; hc < 6; ++hc) {
        if (hc + 2 < 6) LOADCHUNK(hc + 2, ldr[hc & 1])
#pragma unroll
        for (int kk = 0; kk < 2; ++kk) {
            const int gx = kk*4 + fq;
            const bf16x8 ah = *(const bf16x8*)(lds + wbase + fr*128
                                               + ((gx ^ frx7))*16);
            const bf16x8 bw = *(const bf16x8*)(WTg + (hbase + hc)*64 + kk*32);
            acc = __builtin_amdgcn_mfma_f32_16x16x32_bf16(bw, ah, acc, 0, 0, 0);
        }
        if (hc + 1 < 6) CVTWRITE(ldr[(hc + 1) & 1])  // same-wave: no barrier
    }

    // write this wave's partials (acc + stats) to its trans slice
    float* trans = (float*)(lds + 22784);
    float* trp = trans + (p*2 + sb)*304;   // [16][19]
#pragma unroll
    for (int i = 0; i < 4; ++i)
        trp[fr*19 + fq*4 + i] = acc[i];
    s0 += __shfl_xor(s0, 1, 64); s0 += __shfl_xor(s0, 2, 64);
    s1 += __shfl_xor(s1, 1, 64); s1 += __shfl_xor(s1, 2, 64);
    if (lc == 0) { trp[lr*19 + 16] = s0; trp[lr*19 + 17] = s1; }

    __syncthreads();   // THE single barrier: pair merge + KV visibility

    // ---- tail (per-wave, redundant within pair) ----
    const int sg = lane >> 4;
    const int tw = fr;                   // token within pair
    const float* trA = trans + (p*2 + 0)*304;
    const float* trB = trans + (p*2 + 1)*304;
    float fA[16];
#pragma unroll
    for (int k = 0; k < 16; ++k) fA[k] = trA[tw*19 + k] + trB[tw*19 + k];
    const float fS0 = trA[tw*19 + 16] + trB[tw*19 + 16];
    const float fS1 = trA[tw*19 + 17] + trB[tw*19 + 17];

    const float inv_h = 1.0f / 768.0f;
    const float mean1 = fS0 * inv_h;
    const float var1 = fmaf(-mean1, mean1, fS1 * inv_h);
    const float rs1 = rsqrtf(var1 + LN_EPS);
    float d[16];
#pragma unroll
    for (int k = 0; k < 16; ++k)
        d[k] = fmaf(rs1, fmaf(-mean1, ws[WS_G + k], fA[k]), ws[WS_C + k]);

    float t0s = 0.f;
#pragma unroll
    for (int k = 0; k < 16; ++k) t0s += d[k];
    const float mean2 = t0s * 0.0625f;
    float t1s = 0.f;
#pragma unroll
    for (int k = 0; k < 16; ++k) { const float c = d[k] - mean2; t1s = fmaf(c, c, t1s); }
    const float rs2 = rsqrtf(t1s * 0.0625f + LN_EPS);
    float qv[16];
#pragma unroll
    for (int k = 0; k < 16; ++k)
        qv[k] = fmaf((d[k] - mean2) * rs2, g2[k], b2[k]);

    // split softmax (no max-sub: |score| << 1): sg covers 13/13/12/12 memories
    const int mm0 = (sg < 2) ? sg*13 : 26 + (sg - 2)*12;
    const int mm1 = mm0 + ((sg < 2) ? 13 : 12);
    float mo[16];
#pragma unroll
    for (int k = 0; k < 16; ++k) mo[k] = 0.f;
    float ssum = 0.f;
#pragma unroll 1
    for (int mm = mm0; mm < mm1; ++mm) {
        float a = 0.f;
#pragma unroll
        for (int k = 0; k < 16; ++k) a = fmaf(qv[k], KV[mm*16 + k], a);
        const float e = __expf(a);
        ssum += e;
#pragma unroll
        for (int k = 0; k < 16; ++k) mo[k] = fmaf(e, KV[800 + mm*16 + k], mo[k]);
    }
    ssum += __shfl_xor(ssum, 16, 64);
    ssum += __shfl_xor(ssum, 32, 64);
#pragma unroll
    for (int k = 0; k < 16; ++k) {
        mo[k] += __shfl_xor(mo[k], 16, 64);
        mo[k] += __shfl_xor(mo[k], 32, 64);
    }
    const float rn = 1.0f / ssum;
#pragma unroll
    for (int k = 0; k < 16; ++k) mo[k] *= rn;

    float u0 = 0.f;
#pragma unroll
    for (int k = 0; k < 16; ++k) u0 += mo[k];
    const float mean3 = u0 * 0.0625f;
    float u1 = 0.f;
#pragma unroll
    for (int k = 0; k < 16; ++k) { const float c = mo[k] - mean3; u1 = fmaf(c, c, u1); }
    const float rs3 = rsqrtf(u1 * 0.0625f + LN_EPS);

    float4 mq;
    if (sg == 0)      mq = make_float4(mo[0],  mo[1],  mo[2],  mo[3]);
    else if (sg == 1) mq = make_float4(mo[4],  mo[5],  mo[6],  mo[7]);
    else if (sg == 2) mq = make_float4(mo[8],  mo[9],  mo[10], mo[11]);
    else              mq = make_float4(mo[12], mo[13], mo[14], mo[15]);
    const float4 gq = *(const float4*)(g3 + sg*4);
    const float4 bq = *(const float4*)(b3 + sg*4);
    float4 stv;
    stv.x = fmaf((mq.x - mean3) * rs3, gq.x, bq.x);
    stv.y = fmaf((mq.y - mean3) * rs3, gq.y, bq.y);
    stv.z = fmaf((mq.z - mean3) * rs3, gq.z, bq.z);
    stv.w = fmaf((mq.w - mean3) * rs3, gq.w, bq.w);

    // r to pair LDS [16][20]; both waves write identical values (benign dup),
    // each wave's up-phase reads are covered by its OWN writes -> no barrier.
    float* r_lds = (float*)(lds + 27648) + p*320;
    *(float4*)(r_lds + tw*20 + sg*4) = stv;

    // ---- up phase: wave covers its 8 tokens (sb half of pair) x 768 cols ----
#pragma unroll 1
    for (int jg = 0; jg < 3; ++jg) {
        const int j0 = jg * 256 + lane * 4;
        float4 wv[16];
#pragma unroll
        for (int k = 0; k < 16; ++k)
            wv[k] = *(const float4*)(W_up + k*HDIM + j0);
        const float4 bu = *(const float4*)(b_up + j0);
#pragma unroll 2
        for (int tt = 0; tt < 8; ++tt) {
            const int tloc = sb*8 + tt;
            const float* rt = r_lds + tloc*20;   // uniform addr -> broadcast
            float4 a2 = bu;
#pragma unroll
            for (int k = 0; k < 16; ++k) {
                const float rk = rt[k];
                a2.x = fmaf(rk, wv[k].x, a2.x);
                a2.y = fmaf(rk, wv[k].y, a2.y);
                a2.z = fmaf(rk, wv[k].z, a2.z);
                a2.w = fmaf(rk, wv[k].w, a2.w);
            }
            *(float4*)(out + (size_t)(tok0 + tloc) * HDIM + j0) = a2;
        }
    }
}

extern "C" void kernel_launch(void* const* d_in, const int* in_sizes, int n_in,
                              void* d_out, int out_size, void* d_ws, size_t ws_size,
                              hipStream_t stream) {
    const float* x      = (const float*)d_in[0];
    const float* g1     = (const float*)d_in[1];
    const float* b1     = (const float*)d_in[2];
    const float* W_down = (const float*)d_in[3];
    const float* b_down = (const float*)d_in[4];
    const float* g2     = (const float*)d_in[5];
    const float* b2     = (const float*)d_in[6];
    const float* memory = (const float*)d_in[7];
    const float* W_k    = (const float*)d_in[8];
    const float* b_k    = (const float*)d_in[9];
    const float* W_v    = (const float*)d_in[10];
    const float* b_v    = (const float*)d_in[11];
    const float* g3     = (const float*)d_in[12];
    const float* b3     = (const float*)d_in[13];
    const float* W_up   = (const float*)d_in[14];
    const float* b_up   = (const float*)d_in[15];
    float* out = (float*)d_out;
    float* ws  = (float*)d_ws;

    hipLaunchKernelGGL(pre_kernel, dim3(13), dim3(256), 0, stream,
                       g1, b1, W_down, b_down, memory, W_k, b_k, W_v, b_v, ws);
    hipLaunchKernelGGL(fused_kernel, dim3(NTOK/32), dim3(256), 0, stream,
                       x, ws, g2, b2, g3, b3, W_up, b_up, out);
}

// Round 23
// 41.979 us; speedup vs baseline: 8.5310x; 1.5754x over previous
//
#include <hip/hip_runtime.h>
#include <cstdint>

#define LN_EPS 1e-12f
#define NTOK 32768
#define HDIM 768
#define DDIM 16
#define MMEM 50

// ws layout (float offsets)
#define WS_G    0        // 16
#define WS_C    16       // 16 (includes b_down)
#define WS_KEY  32       // 800
#define WS_VAL  832      // 800
#define WS_WT   1632     // 12288 ushorts (bf16 W1^T [16][768]) = 3072 floats

typedef short bf16x8 __attribute__((ext_vector_type(8)));
typedef float f32x4 __attribute__((ext_vector_type(4)));

// bf16 via raw bits (RNE) — for weights
__device__ __forceinline__ unsigned f2bf(float f) {
    const unsigned u = __builtin_bit_cast(unsigned, f);
    return (u + 0x7FFFu + ((u >> 16) & 1u)) >> 16;
}

// 13 blocks: block 0 = G/C + KEY/VAL; blocks 1..12 = WT conversion slices.
__global__ __launch_bounds__(256) void pre_kernel(
    const float* __restrict__ g1, const float* __restrict__ b1,
    const float* __restrict__ W_down, const float* __restrict__ b_down,
    const float* __restrict__ memory, const float* __restrict__ W_k,
    const float* __restrict__ b_k, const float* __restrict__ W_v,
    const float* __restrict__ b_v, float* __restrict__ ws)
{
    const int tid = threadIdx.x;
    const int blk = blockIdx.x;
    if (blk > 0) {
        const int e0 = (blk - 1) * 1024 + tid * 4;
        const int n  = e0 / HDIM;
        const int h  = e0 - n * HDIM;
        const unsigned r0 = f2bf(g1[h+0]*W_down[(h+0)*DDIM+n])
                          | (f2bf(g1[h+1]*W_down[(h+1)*DDIM+n]) << 16);
        const unsigned r1 = f2bf(g1[h+2]*W_down[(h+2)*DDIM+n])
                          | (f2bf(g1[h+3]*W_down[(h+3)*DDIM+n]) << 16);
        *(uint2*)((unsigned short*)(ws + WS_WT) + e0) = make_uint2(r0, r1);
        return;
    }
    __shared__ float redG[16][17];
    __shared__ float redC[16][17];
    const int k = tid & 15, g = tid >> 4;
    float pG = 0.f, pC = 0.f;
    for (int i = g*(HDIM/16); i < (g+1)*(HDIM/16); ++i) {
        const float w = W_down[i*DDIM + k];
        pG = fmaf(g1[i], w, pG);
        pC = fmaf(b1[i], w, pC);
    }
    redG[g][k] = pG; redC[g][k] = pC;
    __syncthreads();
    if (tid < 16) {
        float sG = 0.f, sC = 0.f;
        for (int gg = 0; gg < 16; ++gg) { sG += redG[gg][tid]; sC += redC[gg][tid]; }
        ws[WS_G + tid] = sG;
        ws[WS_C + tid] = sC + b_down[tid];
    }
    for (int e = tid; e < MMEM*DDIM; e += 256) {
        const int m = e >> 4, kk = e & 15;
        float sk = b_k[kk], sv = b_v[kk];
        for (int dd = 0; dd < DDIM; ++dd) {
            const float mv = memory[m*DDIM + dd];
            sk = fmaf(mv, W_k[dd*DDIM + kk], sk);
            sv = fmaf(mv, W_v[dd*DDIM + kk], sv);
        }
        ws[WS_KEY + e] = sk;
        ws[WS_VAL + e] = sv;
    }
}

// per-wave staging: 4 coalesced float4 loads of chunk CC of this wave's
// 16-token tile. Row lr=lane>>2, floats j*16 + lc*4 (64B/row per instr).
#define LOADCHUNK(CC, RR)                                                     \
    {                                                                         \
        _Pragma("unroll")                                                     \
        for (int j = 0; j < 4; ++j)                                           \
            (RR)[j] = *(const float4*)(x + (size_t)(tok0 + lr)*HDIM           \
                                       + (hbase + (CC))*64 + j*16 + lc*4);    \
    }

// truncate-to-bf16 pack + exact fp32 stats into this wave's private buffer.
#define CVTWRITE(RR)                                                          \
    {                                                                         \
        _Pragma("unroll")                                                     \
        for (int j = 0; j < 4; ++j) {                                         \
            const float4 v = (RR)[j];                                         \
            s0 += v.x + v.y + v.z + v.w;                                      \
            s1 = fmaf(v.x,v.x,fmaf(v.y,v.y,fmaf(v.z,v.z,fmaf(v.w,v.w,s1)))); \
            const unsigned ux = __builtin_bit_cast(unsigned, v.x);            \
            const unsigned uy = __builtin_bit_cast(unsigned, v.y);            \
            const unsigned uz = __builtin_bit_cast(unsigned, v.z);            \
            const unsigned uw = __builtin_bit_cast(unsigned, v.w);            \
            const unsigned h01 = (ux >> 16) | (uy & 0xFFFF0000u);             \
            const unsigned h23 = (uz >> 16) | (uw & 0xFFFF0000u);             \
            const int col4 = j*4 + lc;                                        \
            const int gg   = col4 >> 1;                                       \
            const int off_ = wbase + lr*128 + ((gg ^ (lr & 7)))*16            \
                           + (col4 & 1)*8;                                    \
            *(uint2*)(lds + off_) = make_uint2(h01, h23);                     \
        }                                                                     \
    }

// fused, barrier-free waves + NONTEMPORAL out stores (keep x L3-resident).
__global__ __launch_bounds__(256) void fused_kernel(
    const float* __restrict__ x, const float* __restrict__ ws,
    const float* __restrict__ g2, const float* __restrict__ b2,
    const float* __restrict__ g3, const float* __restrict__ b3,
    const float* __restrict__ W_up, const float* __restrict__ b_up,
    float* __restrict__ out)
{
    __shared__ __align__(16) char lds[30208];
    // map: xbuf 4x4KB @0 | KV 6.4KB @16384 | trans 4x304f @22784 | r 2x320f @27648
    const int tid  = threadIdx.x;
    const int lane = tid & 63;
    const int w    = tid >> 6;           // wave 0..3
    const int p    = w >> 1;             // pair 0/1
    const int sb   = w & 1;              // K-half within pair
    const int wbase = w * 4096;          // private x-buf
    const int hbase = sb * 6;            // first chunk of this K-half
    const int t0   = blockIdx.x * 32;
    const int tok0 = t0 + p * 16;        // pair's first token

    const int lr = lane >> 2;            // staging row 0..15
    const int lc = lane & 3;             // staging col quad

    float s0 = 0.f, s1 = 0.f;
    float4 ldr[2][4];

    LOADCHUNK(0, ldr[0])
    LOADCHUNK(1, ldr[1])

    // stage KV (visibility needed only after the single barrier below)
    float* KV = (float*)(lds + 16384);
    {
        const float4* src = (const float4*)(ws + WS_KEY);
        float4* dst = (float4*)KV;
        dst[tid] = src[tid];
        if (tid < 144) dst[256 + tid] = src[256 + tid];
    }

    CVTWRITE(ldr[0])

    f32x4 acc = {0.f, 0.f, 0.f, 0.f};
    const int fr   = lane & 15;          // MFMA x-row (token within pair)
    const int frx7 = fr & 7;
    const int fq   = lane >> 4;          // k-quadrant
    const unsigned short* __restrict__ WTg =
        (const unsigned short*)(ws + WS_WT) + (lane & 15)*768 + fq*8;

#pragma unroll
    for (int hc = 0; hc < 6; ++hc) {
        if (hc + 2 < 6) LOADCHUNK(hc + 2, ldr[hc & 1])
#pragma unroll
        for (int kk = 0; kk < 2; ++kk) {
            const int gx = kk*4 + fq;
            const bf16x8 ah = *(const bf16x8*)(lds + wbase + fr*128
                                               + ((gx ^ frx7))*16);
            const bf16x8 bw = *(const bf16x8*)(WTg + (hbase + hc)*64 + kk*32);
            acc = __builtin_amdgcn_mfma_f32_16x16x32_bf16(bw, ah, acc, 0, 0, 0);
        }
        if (hc + 1 < 6) CVTWRITE(ldr[(hc + 1) & 1])  // same-wave: no barrier
    }

    // write this wave's partials (acc + stats) to its trans slice
    float* trans = (float*)(lds + 22784);
    float* trp = trans + (p*2 + sb)*304;   // [16][19]
#pragma unroll
    for (int i = 0; i < 4; ++i)
        trp[fr*19 + fq*4 + i] = acc[i];
    s0 += __shfl_xor(s0, 1, 64); s0 += __shfl_xor(s0, 2, 64);
    s1 += __shfl_xor(s1, 1, 64); s1 += __shfl_xor(s1, 2, 64);
    if (lc == 0) { trp[lr*19 + 16] = s0; trp[lr*19 + 17] = s1; }

    __syncthreads();   // THE single barrier: pair merge + KV visibility

    // ---- tail (per-wave, redundant within pair) ----
    const int sg = lane >> 4;
    const int tw = fr;                   // token within pair
    const float* trA = trans + (p*2 + 0)*304;
    const float* trB = trans + (p*2 + 1)*304;
    float fA[16];
#pragma unroll
    for (int k = 0; k < 16; ++k) fA[k] = trA[tw*19 + k] + trB[tw*19 + k];
    const float fS0 = trA[tw*19 + 16] + trB[tw*19 + 16];
    const float fS1 = trA[tw*19 + 17] + trB[tw*19 + 17];

    const float inv_h = 1.0f / 768.0f;
    const float mean1 = fS0 * inv_h;
    const float var1 = fmaf(-mean1, mean1, fS1 * inv_h);
    const float rs1 = rsqrtf(var1 + LN_EPS);
    float d[16];
#pragma unroll
    for (int k = 0; k < 16; ++k)
        d[k] = fmaf(rs1, fmaf(-mean1, ws[WS_G + k], fA[k]), ws[WS_C + k]);

    float t0s = 0.f;
#pragma unroll
    for (int k = 0; k < 16; ++k) t0s += d[k];
    const float mean2 = t0s * 0.0625f;
    float t1s = 0.f;
#pragma unroll
    for (int k = 0; k < 16; ++k) { const float c = d[k] - mean2; t1s = fmaf(c, c, t1s); }
    const float rs2 = rsqrtf(t1s * 0.0625f + LN_EPS);
    float qv[16];
#pragma unroll
    for (int k = 0; k < 16; ++k)
        qv[k] = fmaf((d[k] - mean2) * rs2, g2[k], b2[k]);

    // split softmax (no max-sub: |score| << 1): sg covers 13/13/12/12 memories
    const int mm0 = (sg < 2) ? sg*13 : 26 + (sg - 2)*12;
    const int mm1 = mm0 + ((sg < 2) ? 13 : 12);
    float mo[16];
#pragma unroll
    for (int k = 0; k < 16; ++k) mo[k] = 0.f;
    float ssum = 0.f;
#pragma unroll 1
    for (int mm = mm0; mm < mm1; ++mm) {
        float a = 0.f;
#pragma unroll
        for (int k = 0; k < 16; ++k) a = fmaf(qv[k], KV[mm*16 + k], a);
        const float e = __expf(a);
        ssum += e;
#pragma unroll
        for (int k = 0; k < 16; ++k) mo[k] = fmaf(e, KV[800 + mm*16 + k], mo[k]);
    }
    ssum += __shfl_xor(ssum, 16, 64);
    ssum += __shfl_xor(ssum, 32, 64);
#pragma unroll
    for (int k = 0; k < 16; ++k) {
        mo[k] += __shfl_xor(mo[k], 16, 64);
        mo[k] += __shfl_xor(mo[k], 32, 64);
    }
    const float rn = 1.0f / ssum;
#pragma unroll
    for (int k = 0; k < 16; ++k) mo[k] *= rn;

    float u0 = 0.f;
#pragma unroll
    for (int k = 0; k < 16; ++k) u0 += mo[k];
    const float mean3 = u0 * 0.0625f;
    float u1 = 0.f;
#pragma unroll
    for (int k = 0; k < 16; ++k) { const float c = mo[k] - mean3; u1 = fmaf(c, c, u1); }
    const float rs3 = rsqrtf(u1 * 0.0625f + LN_EPS);

    float4 mq;
    if (sg == 0)      mq = make_float4(mo[0],  mo[1],  mo[2],  mo[3]);
    else if (sg == 1) mq = make_float4(mo[4],  mo[5],  mo[6],  mo[7]);
    else if (sg == 2) mq = make_float4(mo[8],  mo[9],  mo[10], mo[11]);
    else              mq = make_float4(mo[12], mo[13], mo[14], mo[15]);
    const float4 gq = *(const float4*)(g3 + sg*4);
    const float4 bq = *(const float4*)(b3 + sg*4);
    float4 stv;
    stv.x = fmaf((mq.x - mean3) * rs3, gq.x, bq.x);
    stv.y = fmaf((mq.y - mean3) * rs3, gq.y, bq.y);
    stv.z = fmaf((mq.z - mean3) * rs3, gq.z, bq.z);
    stv.w = fmaf((mq.w - mean3) * rs3, gq.w, bq.w);

    // r to pair LDS [16][20]; both waves write identical values (benign dup),
    // each wave's up-phase reads are covered by its OWN writes -> no barrier.
    float* r_lds = (float*)(lds + 27648) + p*320;
    *(float4*)(r_lds + tw*20 + sg*4) = stv;

    // ---- up phase: wave covers its 8 tokens (sb half of pair) x 768 cols ----
#pragma unroll 1
    for (int jg = 0; jg < 3; ++jg) {
        const int j0 = jg * 256 + lane * 4;
        float4 wv[16];
#pragma unroll
        for (int k = 0; k < 16; ++k)
            wv[k] = *(const float4*)(W_up + k*HDIM + j0);
        const float4 bu = *(const float4*)(b_up + j0);
#pragma unroll 2
        for (int tt = 0; tt < 8; ++tt) {
            const int tloc = sb*8 + tt;
            const float* rt = r_lds + tloc*20;   // uniform addr -> broadcast
            float4 a2 = bu;
#pragma unroll
            for (int k = 0; k < 16; ++k) {
                const float rk = rt[k];
                a2.x = fmaf(rk, wv[k].x, a2.x);
                a2.y = fmaf(rk, wv[k].y, a2.y);
                a2.z = fmaf(rk, wv[k].z, a2.z);
                a2.w = fmaf(rk, wv[k].w, a2.w);
            }
            // nontemporal: out is write-once/never-read -> don't allocate in
            // L2/L3, preserve x's Infinity-Cache residency. Builtin needs a
            // NATIVE vector type, not HIP's float4 class.
            f32x4 sv = { a2.x, a2.y, a2.z, a2.w };
            __builtin_nontemporal_store(sv,
                (f32x4*)(out + (size_t)(tok0 + tloc) * HDIM + j0));
        }
    }
}

extern "C" void kernel_launch(void* const* d_in, const int* in_sizes, int n_in,
                              void* d_out, int out_size, void* d_ws, size_t ws_size,
                              hipStream_t stream) {
    const float* x      = (const float*)d_in[0];
    const float* g1     = (const float*)d_in[1];
    const float* b1     = (const float*)d_in[2];
    const float* W_down = (const float*)d_in[3];
    const float* b_down = (const float*)d_in[4];
    const float* g2     = (const float*)d_in[5];
    const float* b2     = (const float*)d_in[6];
    const float* memory = (const float*)d_in[7];
    const float* W_k    = (const float*)d_in[8];
    const float* b_k    = (const float*)d_in[9];
    const float* W_v    = (const float*)d_in[10];
    const float* b_v    = (const float*)d_in[11];
    const float* g3     = (const float*)d_in[12];
    const float* b3     = (const float*)d_in[13];
    const float* W_up   = (const float*)d_in[14];
    const float* b_up   = (const float*)d_in[15];
    float* out = (float*)d_out;
    float* ws  = (float*)d_ws;

    hipLaunchKernelGGL(pre_kernel, dim3(13), dim3(256), 0, stream,
                       g1, b1, W_down, b_down, memory, W_k, b_k, W_v, b_v, ws);
    hipLaunchKernelGGL(fused_kernel, dim3(NTOK/32), dim3(256), 0, stream,
                       x, ws, g2, b2, g3, b3, W_up, b_up, out);
}